// Round 4
// baseline (402.497 us; speedup 1.0000x reference)
//
#include <hip/hip_runtime.h>
#include <stdint.h>

typedef float   f32x4  __attribute__((ext_vector_type(4)));
typedef __bf16  bf16x8 __attribute__((ext_vector_type(8)));
typedef uint32_t u32x4 __attribute__((ext_vector_type(4)));

// Round-half-up fp32->bf16 for a pair, packed into one dword: low16 = lo, high16 = hi.
__device__ __forceinline__ uint32_t pack_rnd(float lo, float hi) {
    uint32_t a = __float_as_uint(hi) + 0x8000u;
    uint32_t b = __float_as_uint(lo) + 0x8000u;
    return __builtin_amdgcn_perm(a, b, 0x07060302u); // bytes: a3 a2 b3 b2
}

// ---------------- Pre-kernel: weight [512][1024] fp32 -> Wt [1024][512] bf16 --------------
__global__ __launch_bounds__(256) void wt_prep(const float* __restrict__ w,
                                               uint16_t* __restrict__ wt) {
    int t = blockIdx.x * 256 + threadIdx.x;   // 131072 threads
    int n = t & 1023;
    int c = (t >> 10) << 2;                   // c-quad base, 0..508
    const float* p = w + (size_t)c * 1024 + n;
    float f0 = p[0], f1 = p[1024], f2 = p[2048], f3 = p[3072];
    uint2 r;
    r.x = pack_rnd(f0, f1);
    r.y = pack_rnd(f2, f3);
    *(uint2*)(wt + (size_t)n * 512 + c) = r;
}

// ---------------- Main kernel ------------------------------------------------------------
// v5: X-resident design. Block = 64-pixel m-strip; FULL K=512 X panel staged once in LDS
// (bf16, 64 KB static, 8 subtiles [64][64] with the proven XOR swizzle). Then loop 8
// n-tiles x 8 k-tiles of MFMA with W A-fragments read DIRECTLY from global (Wt is bf16,
// 1 MB, L2-hot; each wave owns a disjoint 16-row n-slice -> no duplication; per-row reads
// are one 64 B sector). NO barriers after staging. 512 threads (8 waves), 2 blocks/CU.
__global__ __launch_bounds__(512, 4) void tconv_gemm(const float* __restrict__ x,
                                                     const uint16_t* __restrict__ wt,
                                                     const float* __restrict__ bias,
                                                     float* __restrict__ out) {
    __shared__ uint16_t lds[32768]; // 64 KB: [sub=8][m=64][k=64] bf16, swizzled

    const int tid  = threadIdx.x;
    const int l    = tid & 63;
    const int wv   = tid >> 6;      // 0..7
    const int l15  = l & 15;
    const int quad = l >> 4;

    const int mblk = blockIdx.x;    // 0..511: b = mblk>>6, input row = mblk&63
    const int b    = mblk >> 6;
    const int row  = mblk & 63;
    const float* xblk = x + (size_t)b * 512 * 4096 + row * 64;

    // ---- stage X: [64 m][512 k] fp32 -> lds, one pass, one barrier ----
    // thread covers 4 m x 8 k per round; kc = k-octet 0..31, two rounds of 256 k.
    const int mq4 = (tid & 15) * 4;
    const int kc  = tid >> 4;               // 0..31
    const int sub0 = kc >> 3;               // 0..3 (round adds +4)
    const int cch  = kc & 7;                // chunk within subtile
    int xw_base[4];
#pragma unroll
    for (int mm = 0; mm < 4; ++mm) {
        int m = mq4 + mm;
        xw_base[mm] = sub0 * 4096 + m * 64 + ((cch ^ ((m >> 1) & 7)) << 3);
    }
    {
        const float* xs0 = xblk + (size_t)(kc * 8) * 4096 + mq4;
        const float* xs1 = xs0 + (size_t)256 * 4096;
        f32x4 va[8], vb[8];
#pragma unroll
        for (int r = 0; r < 8; ++r) va[r] = *(const f32x4*)(xs0 + (size_t)r * 4096);
#pragma unroll
        for (int r = 0; r < 8; ++r) vb[r] = *(const f32x4*)(xs1 + (size_t)r * 4096);
#pragma unroll
        for (int mm = 0; mm < 4; ++mm) {
            u32x4 pk;
            pk.x = pack_rnd(va[0][mm], va[1][mm]);
            pk.y = pack_rnd(va[2][mm], va[3][mm]);
            pk.z = pack_rnd(va[4][mm], va[5][mm]);
            pk.w = pack_rnd(va[6][mm], va[7][mm]);
            *(u32x4*)(lds + xw_base[mm]) = pk;
        }
#pragma unroll
        for (int mm = 0; mm < 4; ++mm) {
            u32x4 pk;
            pk.x = pack_rnd(vb[0][mm], vb[1][mm]);
            pk.y = pack_rnd(vb[2][mm], vb[3][mm]);
            pk.z = pack_rnd(vb[4][mm], vb[5][mm]);
            pk.w = pack_rnd(vb[6][mm], vb[7][mm]);
            *(u32x4*)(lds + 16384 + xw_base[mm]) = pk;
        }
    }
    __syncthreads(); // the ONLY barrier

    // ---- B-fragment (X) LDS read offsets: m = tm*16 + l15, k-chunk = ks*4+quad ----
    int b_off[2][4];
#pragma unroll
    for (int ks = 0; ks < 2; ++ks)
#pragma unroll
        for (int tm = 0; tm < 4; ++tm) {
            int m = tm * 16 + l15;
            b_off[ks][tm] = m * 64 + (((ks * 4 + quad) ^ ((m >> 1) & 7)) << 3);
        }

    // ---- A-fragment (W) global base: wave's n-row = wv*16 + l15, k-chunk = quad ----
    // addr(nblk,kt,ks) = wp + nblk*65536 + kt*64 + ks*32   (elements)
    const uint16_t* wp = wt + ((size_t)(wv * 16 + l15) << 9) + (quad << 3);

    const int y2 = row * 2;
    float* outb = out + (size_t)b * 256 * 16384;

    // prefetch (nblk=0, kt=0)
    bf16x8 a0 = *(const bf16x8*)(wp);
    bf16x8 a1 = *(const bf16x8*)(wp + 32);

    for (int nblk = 0; nblk < 8; ++nblk) {
        float bv = bias[nblk * 32 + wv * 4 + quad];   // issued early, used in epilogue
        const uint16_t* wn = wp + nblk * 65536;

        f32x4 acc[4];
#pragma unroll
        for (int tm = 0; tm < 4; ++tm) acc[tm] = f32x4{0.f, 0.f, 0.f, 0.f};

#pragma unroll
        for (int kt = 0; kt < 8; ++kt) {
            // prefetch next A-fragments (next kt, or next nblk's kt=0; wraps at the end)
            const uint16_t* wnx = (kt < 7) ? (wn + (kt + 1) * 64)
                                           : (wp + ((nblk + 1) & 7) * 65536);
            bf16x8 na0 = *(const bf16x8*)(wnx);
            bf16x8 na1 = *(const bf16x8*)(wnx + 32);

#pragma unroll
            for (int ks = 0; ks < 2; ++ks) {
                bf16x8 bfr[4];
#pragma unroll
                for (int tm = 0; tm < 4; ++tm)
                    bfr[tm] = *(const bf16x8*)(lds + kt * 4096 + b_off[ks][tm]);
#pragma unroll
                for (int tm = 0; tm < 4; ++tm)
                    acc[tm] = __builtin_amdgcn_mfma_f32_16x16x32_bf16(
                        ks == 0 ? a0 : a1, bfr[tm], acc[tm], 0, 0, 0);
            }
            a0 = na0; a1 = na1;
        }

        // ---- epilogue for this n-tile: o = nblk*32 + wv*4 + quad; regs = (i,j) 2x2 ----
        const int o = nblk * 32 + wv * 4 + quad;
        float* p0 = outb + ((size_t)(o * 128 + y2)) * 128 + 2 * l15;
#pragma unroll
        for (int tm = 0; tm < 4; ++tm) {
            f32x4 a = acc[tm];
            float2 t0; t0.x = a.x + bv; t0.y = a.y + bv;   // (i=0, j=0,1)
            float2 t1; t1.x = a.z + bv; t1.y = a.w + bv;   // (i=1, j=0,1)
            *(float2*)(p0 + tm * 32)       = t0;
            *(float2*)(p0 + 128 + tm * 32) = t1;
        }
    }
}

extern "C" void kernel_launch(void* const* d_in, const int* in_sizes, int n_in,
                              void* d_out, int out_size, void* d_ws, size_t ws_size,
                              hipStream_t stream) {
    const float* x    = (const float*)d_in[0];  // [8][512][64][64]
    const float* w    = (const float*)d_in[1];  // [512][256][2][2] = [512][1024]
    const float* bias = (const float*)d_in[2];  // [256]
    float* out        = (float*)d_out;          // [8][256][128][128]
    uint16_t* wt      = (uint16_t*)d_ws;        // [1024][512] bf16 (1 MiB)

    wt_prep<<<512, 256, 0, stream>>>(w, wt);
    tconv_gemm<<<512, 512, 0, stream>>>(x, wt, bias, out);
}

// Round 5
// 205.532 us; speedup vs baseline: 1.9583x; 1.9583x over previous
//
#include <hip/hip_runtime.h>
#include <stdint.h>

#define AS1 __attribute__((address_space(1)))
#define AS3 __attribute__((address_space(3)))

typedef float   f32x4  __attribute__((ext_vector_type(4)));
typedef __bf16  bf16x8 __attribute__((ext_vector_type(8)));
typedef uint32_t u32x4 __attribute__((ext_vector_type(4)));

// Round-half-up fp32->bf16 for a pair, packed into one dword: low16 = lo, high16 = hi.
__device__ __forceinline__ uint32_t pack_rnd(float lo, float hi) {
    uint32_t a = __float_as_uint(hi) + 0x8000u;
    uint32_t b = __float_as_uint(lo) + 0x8000u;
    return __builtin_amdgcn_perm(a, b, 0x07060302u); // bytes: a3 a2 b3 b2
}

// ---------------- Pre-kernel: weight [512][1024] fp32 -> Wt [1024][512] bf16 --------------
__global__ __launch_bounds__(256) void wt_prep(const float* __restrict__ w,
                                               uint16_t* __restrict__ wt) {
    int t = blockIdx.x * 256 + threadIdx.x;   // 131072 threads
    int n = t & 1023;
    int c = (t >> 10) << 2;                   // c-quad base, 0..508
    const float* p = w + (size_t)c * 1024 + n;
    float f0 = p[0], f1 = p[1024], f2 = p[2048], f3 = p[3072];
    uint2 r;
    r.x = pack_rnd(f0, f1);
    r.y = pack_rnd(f2, f3);
    *(uint2*)(wt + (size_t)n * 512 + c) = r;
}

// ---------------- Main kernel -------------------------------------------------------------
// v6: X-resident. Block = 128-pixel m-strip; full K=512 X panel staged ONCE in LDS (bf16,
// 128 KB, [kt64=8][m=128][chunk=8] with proven XOR swizzle). Loop 8 n-tiles x 16 k32-steps;
// W(s) [128n][32k] tiles streamed via global_load_lds (L2-hot, proven cheap in v4) into a
// 4-deep 8 KB ring, prefetch distance 3, ONE barrier + vmcnt(2) per step (never drained).
// X L2/L3 traffic /8 vs v4. 512 threads (8 waves), 160 KB dynamic LDS, 1 block/CU, grid=256.
__global__ __launch_bounds__(512, 2) void tconv_gemm(const float* __restrict__ x,
                                                     const uint16_t* __restrict__ wt,
                                                     const float* __restrict__ bias,
                                                     float* __restrict__ out) {
    extern __shared__ uint16_t lds[]; // [0,65536): X panel; [65536,81920): W ring 4x4096

    const int tid  = threadIdx.x;
    const int l    = tid & 63;
    const int wv   = tid >> 6;      // 0..7
    const int l15  = l & 15;
    const int quad = l >> 4;

    const int blk = blockIdx.x;     // 0..255
    const int b   = blk >> 5;       // batch
    const int p0  = (blk & 31) * 128;
    const float* xblk = x + (size_t)b * 512 * 4096 + p0;

    // ---- X staging constants: thread covers 4m x 8k per round, 4 rounds of 128 k ----
    const int mq4 = (tid & 31) * 4;
    const int ko  = tid >> 5;                 // 0..15 (k-octet within round)
    const float* xsrc = xblk + (size_t)(ko * 8) * 4096 + mq4;
    int xw0[4];
#pragma unroll
    for (int mm = 0; mm < 4; ++mm) {
        int m = mq4 + mm;
        xw0[mm] = (ko >> 3) * 8192 + m * 64 + (((ko & 7) ^ ((m >> 1) & 7)) << 3);
    }

    // ---- W gll constants: wave stages rows [wv*16, wv*16+16) of each [128][32] tile ----
    const int rr = l >> 2, cc = l & 3;
    const int R  = wv * 16 + rr;              // row within tile
    const uint16_t* wbase = wt + R * 512 + ((cc ^ ((R >> 1) & 3)) << 3); // pre-swizzled src

    // ---- fragment offsets ----
    const int wave_n = (wv >> 2) * 64;        // {0,64}
    const int wave_m = (wv & 3) * 32;         // {0,32,64,96}
    int aoff[4];
#pragma unroll
    for (int tn = 0; tn < 4; ++tn) {
        int n = wave_n + tn * 16 + l15;
        aoff[tn] = 65536 + n * 32 + ((quad ^ ((n >> 1) & 3)) << 3);
    }
    int boff[2][2];
#pragma unroll
    for (int p = 0; p < 2; ++p)
#pragma unroll
        for (int tm = 0; tm < 2; ++tm) {
            int m = wave_m + tm * 16 + l15;
            boff[p][tm] = m * 64 + (((p * 4 + quad) ^ ((m >> 1) & 7)) << 3);
        }

#define PACKW(VB, DST)                                                    \
    {                                                                     \
        _Pragma("unroll")                                                 \
        for (int mm = 0; mm < 4; ++mm) {                                  \
            u32x4 pk;                                                     \
            pk.x = pack_rnd(VB[0][mm], VB[1][mm]);                        \
            pk.y = pack_rnd(VB[2][mm], VB[3][mm]);                        \
            pk.z = pack_rnd(VB[4][mm], VB[5][mm]);                        \
            pk.w = pack_rnd(VB[6][mm], VB[7][mm]);                        \
            *(u32x4*)(lds + xw0[mm] + (DST)) = pk;                        \
        }                                                                 \
    }

    // ---- stage X panel (once) ----
    {
        f32x4 va[8], vb[8];
#pragma unroll
        for (int r = 0; r < 8; ++r) va[r] = *(const f32x4*)(xsrc + (size_t)r * 4096);
        const float* x1 = xsrc + (size_t)128 * 4096;
#pragma unroll
        for (int r = 0; r < 8; ++r) vb[r] = *(const f32x4*)(x1 + (size_t)r * 4096);
        PACKW(va, 0)
        const float* x2 = xsrc + (size_t)256 * 4096;
#pragma unroll
        for (int r = 0; r < 8; ++r) va[r] = *(const f32x4*)(x2 + (size_t)r * 4096);
        PACKW(vb, 16384)
        const float* x3 = xsrc + (size_t)384 * 4096;
#pragma unroll
        for (int r = 0; r < 8; ++r) vb[r] = *(const f32x4*)(x3 + (size_t)r * 4096);
        // W(0),W(1),W(2) gll (newest in queue; all X loads above get consumed by packs)
#pragma unroll
        for (int j = 0; j < 3; ++j)
            __builtin_amdgcn_global_load_lds((AS1 void*)(wbase + j * 32),
                                             (AS3 void*)(lds + 65536 + j * 4096 + wv * 512),
                                             16, 0, 0);
        PACKW(va, 32768)
        PACKW(vb, 49152)
    }
    // stage done: X writes visible, W(0) landed; W(1),W(2) stay in flight
    asm volatile("s_waitcnt vmcnt(2) lgkmcnt(0)" ::: "memory");
    __builtin_amdgcn_sched_barrier(0);
    __builtin_amdgcn_s_barrier();
    __builtin_amdgcn_sched_barrier(0);

    f32x4 acc[4][2];
#pragma unroll
    for (int tn = 0; tn < 4; ++tn)
#pragma unroll
        for (int tm = 0; tm < 2; ++tm) acc[tn][tm] = f32x4{0.f, 0.f, 0.f, 0.f};

    const int y_base = (blk & 31) * 4;
    float* outb = out + (size_t)b * 256 * 16384;
    const int obase0 = (wv >> 2) * 16 + quad;

#define STEP_BODY(T)                                                                   \
    {                                                                                  \
        bf16x8 af[4], bq[2];                                                           \
        _Pragma("unroll")                                                              \
        for (int tn = 0; tn < 4; ++tn)                                                 \
            af[tn] = *(const bf16x8*)(lds + ((T) & 3) * 4096 + aoff[tn]);              \
        _Pragma("unroll")                                                              \
        for (int tm = 0; tm < 2; ++tm)                                                 \
            bq[tm] = *(const bf16x8*)(lds + ((T) >> 1) * 8192 + boff[(T) & 1][tm]);    \
        _Pragma("unroll")                                                              \
        for (int tn = 0; tn < 4; ++tn)                                                 \
            _Pragma("unroll")                                                          \
            for (int tm = 0; tm < 2; ++tm)                                             \
                acc[tn][tm] = __builtin_amdgcn_mfma_f32_16x16x32_bf16(                 \
                    af[tn], bq[tm], acc[tn][tm], 0, 0, 0);                             \
    }

#define EPILOGUE(NB)                                                                   \
    {                                                                                  \
        _Pragma("unroll")                                                              \
        for (int tn = 0; tn < 4; ++tn) {                                               \
            int o = (NB) * 32 + obase0 + tn * 4;                                       \
            float bv = bias[o];                                                        \
            _Pragma("unroll")                                                          \
            for (int tm = 0; tm < 2; ++tm) {                                           \
                int loc = wave_m + tm * 16 + l15;                                      \
                int hl  = loc >> 6;                                                    \
                int ww  = loc & 63;                                                    \
                float* p = outb + ((size_t)(o * 128 + y_base + 2 * hl)) * 128 + 2 * ww;\
                f32x4 a = acc[tn][tm];                                                 \
                float2 t0; t0.x = a.x + bv; t0.y = a.y + bv;                           \
                float2 t1; t1.x = a.z + bv; t1.y = a.w + bv;                           \
                *(float2*)(p)       = t0;                                              \
                *(float2*)(p + 128) = t1;                                              \
                acc[tn][tm] = f32x4{0.f, 0.f, 0.f, 0.f};                               \
            }                                                                          \
        }                                                                              \
    }

    // ---- main: nblk 0..6 (steady), each 16 k32-steps; prefetch distance 3 ----
    const uint16_t* wcur = wbase;           // + nblk*65536
    for (int nblk = 0; nblk < 7; ++nblk) {
#pragma unroll
        for (int t = 0; t < 16; ++t) {
            const uint16_t* wsrc = (t < 13) ? (wcur + (t + 3) * 32)
                                            : (wcur + 65536 + (t - 13) * 32);
            __builtin_amdgcn_global_load_lds((AS1 void*)wsrc,
                (AS3 void*)(lds + 65536 + ((t + 3) & 3) * 4096 + wv * 512), 16, 0, 0);
            STEP_BODY(t)
            asm volatile("s_waitcnt vmcnt(2) lgkmcnt(0)" ::: "memory");
            __builtin_amdgcn_sched_barrier(0);
            __builtin_amdgcn_s_barrier();
            __builtin_amdgcn_sched_barrier(0);
        }
        EPILOGUE(nblk)
        wcur += 65536;
    }

    // ---- tail nblk = 7: static s = 112+t, drain the ring exactly ----
#pragma unroll
    for (int t = 0; t < 16; ++t) {
        if (t < 13)
            __builtin_amdgcn_global_load_lds((AS1 void*)(wcur + (t + 3) * 32),
                (AS3 void*)(lds + 65536 + ((t + 3) & 3) * 4096 + wv * 512), 16, 0, 0);
        STEP_BODY(t)
        if (t < 13) {
            asm volatile("s_waitcnt vmcnt(2) lgkmcnt(0)" ::: "memory");
        } else if (t == 13) {
            asm volatile("s_waitcnt vmcnt(1) lgkmcnt(0)" ::: "memory");
        } else if (t == 14) {
            asm volatile("s_waitcnt vmcnt(0) lgkmcnt(0)" ::: "memory");
        }
        if (t < 15) {
            __builtin_amdgcn_sched_barrier(0);
            __builtin_amdgcn_s_barrier();
            __builtin_amdgcn_sched_barrier(0);
        }
    }
    EPILOGUE(7)

#undef STEP_BODY
#undef EPILOGUE
#undef PACKW
}

extern "C" void kernel_launch(void* const* d_in, const int* in_sizes, int n_in,
                              void* d_out, int out_size, void* d_ws, size_t ws_size,
                              hipStream_t stream) {
    const float* x    = (const float*)d_in[0];  // [8][512][64][64]
    const float* w    = (const float*)d_in[1];  // [512][256][2][2] = [512][1024]
    const float* bias = (const float*)d_in[2];  // [256]
    float* out        = (float*)d_out;          // [8][256][128][128]
    uint16_t* wt      = (uint16_t*)d_ws;        // [1024][512] bf16 (1 MiB)

    // 160 KB dynamic LDS (X 128 KB + W ring 32 KB); gfx950 allows full 160 KB/workgroup.
    hipFuncSetAttribute((const void*)tconv_gemm,
                        hipFuncAttributeMaxDynamicSharedMemorySize, 163840);

    wt_prep<<<512, 256, 0, stream>>>(w, wt);
    tconv_gemm<<<256, 512, 163840, stream>>>(x, wt, bias, out);
}